// Round 6
// baseline (428.350 us; speedup 1.0000x reference)
//
#include <hip/hip_runtime.h>
#include <hip/hip_bf16.h>

#define FEAT 1024
#define EMBED 128
#define CAP 64          // per-node bucket capacity (Poisson mean deg = 16)
#define OVF_CAP 4096    // overflow list capacity

typedef __attribute__((ext_vector_type(8))) short short8;
typedef __attribute__((ext_vector_type(4))) float floatx4;

__device__ inline ushort f2bf(float f) {
    __hip_bfloat16 h = __float2bfloat16(f);
    return *reinterpret_cast<ushort*>(&h);
}
__device__ inline float bfbits_lo(uint u) {        // low 16 bits as bf16 -> f32
    uint v = u << 16; return *reinterpret_cast<float*>(&v);
}
__device__ inline float bfbits_hi(uint u) {        // high 16 bits as bf16 -> f32
    uint v = u & 0xffff0000u; return *reinterpret_cast<float*>(&v);
}

// async 16B global -> LDS (wave-uniform LDS base; HW adds lane*16; global src per-lane)
__device__ inline void async_copy16(const void* g, void* l) {
    __builtin_amdgcn_global_load_lds(
        (const __attribute__((address_space(1))) void*)g,
        (__attribute__((address_space(3))) void*)l, 16, 0, 0);
}
__device__ inline void wait_vm8() {
    asm volatile("s_waitcnt vmcnt(8)" ::: "memory");
    __builtin_amdgcn_sched_barrier(0);
}
__device__ inline void wait_vm0() {
    asm volatile("s_waitcnt vmcnt(0)" ::: "memory");
    __builtin_amdgcn_sched_barrier(0);
}

// --- kernel 1: W fp32 -> bf16, swizzled into MFMA-fragment-linear order ------
// wbs[((s*8 + t)*64 + lane)*8 + j] = bf16(W[t*16 + (lane&15)][s*32 + (lane>>4)*8 + j])
__global__ void swizzle_weight_kernel(const float* __restrict__ w,
                                      ushort* __restrict__ wbs) {
    int gid = blockIdx.x * blockDim.x + threadIdx.x;   // 16384 threads
    int l = gid & 63;
    int t = (gid >> 6) & 7;
    int s = gid >> 9;
    int row = t * 16 + (l & 15);
    int col = s * 32 + (l >> 4) * 8;
    const float* src = w + (size_t)row * FEAT + col;
    float4 v0 = *(const float4*)(src);
    float4 v1 = *(const float4*)(src + 4);
    short8 o;
    o[0] = f2bf(v0.x); o[1] = f2bf(v0.y); o[2] = f2bf(v0.z); o[3] = f2bf(v0.w);
    o[4] = f2bf(v1.x); o[5] = f2bf(v1.y); o[6] = f2bf(v1.z); o[7] = f2bf(v1.w);
    *(short8*)(wbs + (size_t)gid * 8) = o;
}

// --- kernel 2: bucket edges by destination (standalone again) ----------------
__global__ void bucket_fill_kernel(const int* __restrict__ adj_row,
                                   const int* __restrict__ adj_col,
                                   const float* __restrict__ adj_vals,
                                   int* __restrict__ cnt,
                                   int2* __restrict__ bucket,
                                   int* __restrict__ ovf_cnt,
                                   int* __restrict__ ovf_list,
                                   int n_edges) {
    int e = blockIdx.x * blockDim.x + threadIdx.x;
    if (e >= n_edges) return;
    int r = adj_row[e];
    int slot = atomicAdd(&cnt[r], 1);
    if (slot < CAP) {
        bucket[(size_t)r * CAP + slot] = make_int2(adj_col[e], __float_as_int(adj_vals[e]));
    } else {
        int oi = atomicAdd(ovf_cnt, 1);
        if (oi < OVF_CAP) ovf_list[oi] = e;
    }
}

// --- kernel 3: h = x @ W^T, burst-granule A staging ---------------------------
// 4 waves x 16 rows = 64 rows/block. K in 8 octets of 128 feats (512 B/row).
// A path: each wave reg-loads its 16 rows in 512 B CONTIGUOUS bursts (one
// instr = 2 full row-segments of 512 B) -> ds_write into a wave-private
// XOR-swizzled LDS tile (dbuf, 64 KB). This replaces the 256 B-granule
// 49K-concurrent-stream scatter that pinned rounds 3-5 at ~1.4 TB/s.
// B path: octet staged from L2-hot wbs via global_load_lds (32 KB single buf).
// Counted vmcnt(8) waits keep the next octet's 8 A-loads in flight across
// both barriers; vmcnt never drains to 0 mid-loop.
__launch_bounds__(256, 1)
__global__ void gemm_xwT_kernel(const float* __restrict__ x,
                                const ushort* __restrict__ wbs,
                                ushort* __restrict__ hb, int n_nodes) {
    __shared__ __align__(16) char Alds[4 * 2 * 8192];   // wave x buf x (16 rows x 512 B)
    __shared__ __align__(16) char Blds[32768];          // 1 octet: 4 ksteps x 8 KB

    const int lane = threadIdx.x & 63;
    const int wave = threadIdx.x >> 6;
    const int q    = lane >> 4;
    const int m    = lane & 15;
    const int base = blockIdx.x * 64 + wave * 16;

    const char* xb  = (const char*)x;
    const char* wbb = (const char*)wbs;

    // A-load addressing: instr i covers rows {2i, 2i+1} of the wave's slice;
    // lanes 0-31 -> row 2i (bytes (l&31)*16), lanes 32-63 -> row 2i+1.
    const int rl_half = lane >> 5;
    const int cb      = (lane & 31) * 16;               // 0..496
    uint arow[8];
#pragma unroll
    for (int i = 0; i < 8; ++i) {
        int rl = 2 * i + rl_half;
        int rg = base + rl;
        if (rg >= n_nodes) rg = n_nodes - 1;
        arow[i] = (uint)rg * (FEAT * 4) + cb;
    }

    float4 Areg[8];
#define A_LOAD(oct_) do {                                                     \
        _Pragma("unroll")                                                     \
        for (int i = 0; i < 8; ++i)                                           \
            Areg[i] = *(const float4*)(xb + (size_t)arow[i] + (oct_) * 512);  \
    } while (0)

#define A_WRITE(oct_) do {                                                    \
        char* Ab_ = Alds + (wave * 2 + ((oct_) & 1)) * 8192;                  \
        _Pragma("unroll")                                                     \
        for (int i = 0; i < 8; ++i) {                                         \
            int rl_ = 2 * i + rl_half;                                        \
            *(float4*)(Ab_ + rl_ * 512 + (cb ^ ((rl_ & 7) << 4))) = Areg[i];  \
        }                                                                     \
    } while (0)

#define B_DMA(oct_) do {                                                      \
        const char* bs_ = wbb + (size_t)(oct_) * 32768 + wave * 8192 + lane * 16; \
        char* bd_ = Blds + wave * 8192;                                       \
        _Pragma("unroll")                                                     \
        for (int k = 0; k < 8; ++k)                                           \
            async_copy16(bs_ + k * 1024, bd_ + k * 1024);                     \
    } while (0)

    floatx4 acc[8];
#pragma unroll
    for (int t = 0; t < 8; ++t) acc[t] = (floatx4)(0.0f);

    // prologue
    A_LOAD(0);
    wait_vm0();
    A_WRITE(0);
    B_DMA(0);            // 8 outstanding
    A_LOAD(1);           // 16 outstanding
    wait_vm8();          // drains B(0) (older); A(1) stays in flight
    asm volatile("s_waitcnt lgkmcnt(0)" ::: "memory");
    __builtin_amdgcn_sched_barrier(0);
    __builtin_amdgcn_s_barrier();

    const int xk = (m & 7) << 4;
#pragma unroll
    for (int o = 0; o < 8; ++o) {
        // ---- compute octet o (A from buf[o&1], B from Blds) ----
        const char* Ab = Alds + (wave * 2 + (o & 1)) * 8192;
#pragma unroll
        for (int sl = 0; sl < 4; ++sl) {
            float4 alo = *(const float4*)(Ab + m * 512 + ((sl * 128 + q * 32)      ^ xk));
            float4 ahi = *(const float4*)(Ab + m * 512 + ((sl * 128 + q * 32 + 16) ^ xk));
            const char* bsrc = Blds + sl * 8192 + lane * 16;
            short8 bf[8];
#pragma unroll
            for (int t = 0; t < 8; ++t) bf[t] = *(const short8*)(bsrc + t * 1024);

            short8 af;
            af[0] = f2bf(alo.x); af[1] = f2bf(alo.y);
            af[2] = f2bf(alo.z); af[3] = f2bf(alo.w);
            af[4] = f2bf(ahi.x); af[5] = f2bf(ahi.y);
            af[6] = f2bf(ahi.z); af[7] = f2bf(ahi.w);

#pragma unroll
            for (int t = 0; t < 8; ++t)
                acc[t] = __builtin_amdgcn_mfma_f32_16x16x32_bf16(af, bf[t], acc[t], 0, 0, 0);
        }

        if (o < 7) {
            asm volatile("s_waitcnt lgkmcnt(0)" ::: "memory");   // B reads retired
            __builtin_amdgcn_sched_barrier(0);
            __builtin_amdgcn_s_barrier();        // bar1: Blds free for overwrite
            B_DMA(o + 1);                        // A(o+1)[8] + B(o+1)[8] in flight
            wait_vm8();                          // A(o+1) landed in regs
            A_WRITE(o + 1);                      // into buf[(o+1)&1]
            if (o < 6) {
                A_LOAD(o + 2);                   // B(o+1)[8] + A(o+2)[8]
                wait_vm8();                      // B(o+1) landed (older)
            } else {
                wait_vm0();                      // last B: full drain
            }
            asm volatile("s_waitcnt lgkmcnt(0)" ::: "memory");   // A writes visible
            __builtin_amdgcn_sched_barrier(0);
            __builtin_amdgcn_s_barrier();        // bar2: octet o+1 ready
        }
    }
#undef A_LOAD
#undef A_WRITE
#undef B_DMA

#pragma unroll
    for (int t = 0; t < 8; ++t) {
#pragma unroll
        for (int r = 0; r < 4; ++r) {
            int rr = base + q * 4 + r;
            if (rr < n_nodes)
                hb[(size_t)rr * EMBED + t * 16 + m] = f2bf(acc[t][r]);
        }
    }
}

// --- kernel 4: per-node gather-accumulate (UNCHANGED from round 5) -----------
__launch_bounds__(256)
__global__ void gather_kernel(const int* __restrict__ cnt,
                              const int2* __restrict__ bucket,
                              const ushort* __restrict__ hb,
                              const int* __restrict__ ovf_cnt,
                              const int* __restrict__ ovf_list,
                              const int* __restrict__ adj_row,
                              const int* __restrict__ adj_col,
                              const float* __restrict__ adj_vals,
                              float* __restrict__ out, int n_nodes) {
    int node = __builtin_amdgcn_readfirstlane(blockIdx.x * 4 + (threadIdx.x >> 6));
    if (node >= n_nodes) return;
    int lane = threadIdx.x & 63;
    int c_raw = cnt[node];
    int c = c_raw > CAP ? CAP : c_raw;
    const int2* bp = bucket + (size_t)node * CAP;
    const ushort* hl = hb + lane * 2;

    float accx = 0.0f, accy = 0.0f;
    int nb = c >> 4;
    if (nb > 0) {
        int4 eb[8];
#pragma unroll
        for (int i = 0; i < 8; ++i) eb[i] = *(const int4*)(bp + i * 2);
        for (int b = 0; b < nb; ++b) {
            uint u[16]; float wv[16];
#pragma unroll
            for (int i = 0; i < 8; ++i) {
                u[2*i]   = *(const uint*)(hl + (size_t)eb[i].x * EMBED);
                u[2*i+1] = *(const uint*)(hl + (size_t)eb[i].z * EMBED);
                wv[2*i]   = __int_as_float(eb[i].y);
                wv[2*i+1] = __int_as_float(eb[i].w);
            }
            if (b + 1 < nb) {
#pragma unroll
                for (int i = 0; i < 8; ++i)
                    eb[i] = *(const int4*)(bp + (b + 1) * 16 + i * 2);
            }
#pragma unroll
            for (int i = 0; i < 16; ++i) {
                accx = fmaf(wv[i], bfbits_lo(u[i]), accx);
                accy = fmaf(wv[i], bfbits_hi(u[i]), accy);
            }
        }
    }
    int j = nb * 16;
    if (j + 8 <= c) {
        int4 eb[4];
#pragma unroll
        for (int i = 0; i < 4; ++i) eb[i] = *(const int4*)(bp + j + i * 2);
        uint u[8]; float wv[8];
#pragma unroll
        for (int i = 0; i < 4; ++i) {
            u[2*i]   = *(const uint*)(hl + (size_t)eb[i].x * EMBED);
            u[2*i+1] = *(const uint*)(hl + (size_t)eb[i].z * EMBED);
            wv[2*i]   = __int_as_float(eb[i].y);
            wv[2*i+1] = __int_as_float(eb[i].w);
        }
#pragma unroll
        for (int i = 0; i < 8; ++i) {
            accx = fmaf(wv[i], bfbits_lo(u[i]), accx);
            accy = fmaf(wv[i], bfbits_hi(u[i]), accy);
        }
        j += 8;
    }
    for (; j + 2 <= c; j += 2) {
        int4 e01 = *(const int4*)(bp + j);
        uint u0 = *(const uint*)(hl + (size_t)e01.x * EMBED);
        uint u1 = *(const uint*)(hl + (size_t)e01.z * EMBED);
        float w0 = __int_as_float(e01.y), w1 = __int_as_float(e01.w);
        accx = fmaf(w0, bfbits_lo(u0), accx);  accy = fmaf(w0, bfbits_hi(u0), accy);
        accx = fmaf(w1, bfbits_lo(u1), accx);  accy = fmaf(w1, bfbits_hi(u1), accy);
    }
    if (j < c) {
        int2 ev = bp[j];
        uint u = *(const uint*)(hl + (size_t)ev.x * EMBED);
        float w = __int_as_float(ev.y);
        accx = fmaf(w, bfbits_lo(u), accx);
        accy = fmaf(w, bfbits_hi(u), accy);
    }
    if (c_raw > CAP) {
        int n = *ovf_cnt;
        if (n > OVF_CAP) n = OVF_CAP;
        for (int i = 0; i < n; ++i) {
            int e = ovf_list[i];
            if (adj_row[e] == node) {
                uint u = *(const uint*)(hl + (size_t)adj_col[e] * EMBED);
                float w = adj_vals[e];
                accx = fmaf(w, bfbits_lo(u), accx);
                accy = fmaf(w, bfbits_hi(u), accy);
            }
        }
    }
    *(float2*)(out + (size_t)node * EMBED + lane * 2) = make_float2(accx, accy);
}

extern "C" void kernel_launch(void* const* d_in, const int* in_sizes, int n_in,
                              void* d_out, int out_size, void* d_ws, size_t ws_size,
                              hipStream_t stream) {
    const float* x        = (const float*)d_in[0];
    const float* w        = (const float*)d_in[1];
    const int*   adj_row  = (const int*)d_in[2];
    const int*   adj_col  = (const int*)d_in[3];
    const float* adj_vals = (const float*)d_in[4];

    const int n_nodes = in_sizes[0] / FEAT;
    const int n_edges = in_sizes[2];
    float* out = (float*)d_out;

    // workspace layout (bytes):
    //   [wbs 256KB][hb n*128*2][cnt n*4][ovf_cnt 4][ovf_list][pad->16][bucket n*CAP*8]
    char* ws = (char*)d_ws;
    ushort* wbs = (ushort*)ws;
    size_t off = 262144;
    ushort* hb = (ushort*)(ws + off);
    off += (size_t)n_nodes * EMBED * sizeof(ushort);
    char* meta = ws + off;
    int* cnt      = (int*)meta;
    int* ovf_cnt  = (int*)(meta + (size_t)n_nodes * 4);
    int* ovf_list = ovf_cnt + 1;
    size_t meta_bytes = ((size_t)n_nodes * 4 + 4 + OVF_CAP * 4 + 15) & ~(size_t)15;
    int2* bucket = (int2*)(meta + meta_bytes);

    hipMemsetAsync(meta, 0, meta_bytes, stream);

    bucket_fill_kernel<<<(n_edges + 255) / 256, 256, 0, stream>>>(
        adj_row, adj_col, adj_vals, cnt, bucket, ovf_cnt, ovf_list, n_edges);

    swizzle_weight_kernel<<<64, 256, 0, stream>>>(w, wbs);

    gemm_xwT_kernel<<<(n_nodes + 63) / 64, 256, 0, stream>>>(x, wbs, hb, n_nodes);

    gather_kernel<<<(n_nodes + 3) / 4, 256, 0, stream>>>(
        cnt, bucket, hb, ovf_cnt, ovf_list, adj_row, adj_col, adj_vals,
        out, n_nodes);
}